// Round 5
// baseline (211.473 us; speedup 1.0000x reference)
//
#include <hip/hip_runtime.h>

// B=4, S=2048, D=1024. out = softmax((x@Wk)(x@Wq)^T / 32) @ (x@Wv), fp32 out.
// GEMMs: BM=256 tiles, BK=64, 8 waves (2x4), double-buffered LDS,
// 2-deep counted-vmcnt pipeline (stage->wait distance = 1 full K-tile),
// 2 barriers per K-tile, XOR-swizzled LDS, XCD swizzle, setprio.
// Softmax fused: scores writes exp(s/32) bf16; pv row-sums from A-frags, scales 1/l.

typedef __attribute__((ext_vector_type(8))) short bf16x8;
typedef __attribute__((ext_vector_type(4))) float f32x4;

__device__ __forceinline__ unsigned short f2bf(float f) {
    unsigned int u = __float_as_uint(f);
    u += 0x7fff + ((u >> 16) & 1);   // RNE
    return (unsigned short)(u >> 16);
}
__device__ __forceinline__ float bf2f(unsigned short s) {
    return __uint_as_float((unsigned int)s << 16);
}

__device__ __forceinline__ void gld_lds16(const unsigned short* g, unsigned short* l) {
    __builtin_amdgcn_global_load_lds(
        (const __attribute__((address_space(1))) void*)g,
        (__attribute__((address_space(3))) void*)l, 16, 0, 0);
}

template<int N> __device__ __forceinline__ void vmcnt_wait() {
    if constexpr (N == 0) asm volatile("s_waitcnt vmcnt(0)" ::: "memory");
    else if constexpr (N == 6) asm volatile("s_waitcnt vmcnt(6)" ::: "memory");
    else if constexpr (N == 8) asm volatile("s_waitcnt vmcnt(8)" ::: "memory");
}
__device__ __forceinline__ void lgkm0() {
    asm volatile("s_waitcnt lgkmcnt(0)" ::: "memory");
}
__device__ __forceinline__ void bar() {
    asm volatile("" ::: "memory");
    __builtin_amdgcn_s_barrier();
    asm volatile("" ::: "memory");
}

// ---------------- 2-deep pipelined BM=256 x BN x (64*KT) bf16 B^T GEMM ----------------
// C[m,n] = sum_k A[bm+m,k]*B[bn+n,k].  Waves 2(m) x 4(n), wave tile 128 x BN/4.
// LDS: 2 buffers per operand; row = 64B (32 bf16); phys 16B-unit = kg ^ ((lr>>1)&3)
// (2-way bank alias = free). Stage: inverse-swizzled global src, linear gld_lds dest.
// Pipeline: prologue stages tiles 0,1; per-tile trailer stages kt+2 into the
// just-read buffer; single counted vmcnt(L) per tile; 2 barriers per tile.
template<int BN, int KT, bool RS>
__device__ __forceinline__ void gemm8(
    const unsigned short* __restrict__ A, const unsigned short* __restrict__ B,
    int lda, int ldb, int bm, int bn,
    unsigned short* As, unsigned short* Bs,
    f32x4 (&acc)[8][BN/64], float (&rs)[8])
{
    constexpr int NFR = BN / 64;          // B fragments per kk
    constexpr int LB  = BN / 128;         // B gld_lds per k-half
    constexpr int L   = 4 + 2 * LB;       // loads per thread per K-tile (A=4, B=2*LB)
    const int tid  = threadIdx.x;
    const int lane = tid & 63;
    const int wave = tid >> 6;
    const int wr = wave >> 2, wc = wave & 3;
    const int lr = lane & 15, kg = lane >> 4;

    // stage map: thread t -> row (t>>2), unit t&3; global source unit = (t&3)^((t>>3)&3)
    const int srow = tid >> 2;
    const int soff = ((tid & 3) ^ ((tid >> 3) & 3)) * 8;
    const unsigned short* pa0 = A + (size_t)(bm + srow) * lda + soff;
    const unsigned short* pa1 = A + (size_t)(bm + 128 + srow) * lda + soff;
    const unsigned short* pb0 = B + (size_t)(bn + srow) * ldb + soff;
    const unsigned short* pb1 = B + (size_t)(bn + 128 + srow) * ldb + soff;  // BN==256 only

    // read-side swizzled unit
    const int runit = (kg ^ ((lr >> 1) & 3)) * 8;
    const int arow  = (wr * 128 + lr) * 32 + runit;
    const int brow  = (wc * (BN / 4) + lr) * 32 + runit;

    auto stage = [&](int buf, int kt) {
        unsigned short* da = As + buf * 16384 + wave * 512;
        unsigned short* db = Bs + buf * (BN * 64) + wave * 512;
        const int o0 = kt * 64, o1 = kt * 64 + 32;
        gld_lds16(pa0 + o0, da);
        gld_lds16(pa1 + o0, da + 4096);
        gld_lds16(pa0 + o1, da + 8192);
        gld_lds16(pa1 + o1, da + 8192 + 4096);
        gld_lds16(pb0 + o0, db);
        if constexpr (BN == 256) gld_lds16(pb1 + o0, db + 4096);
        gld_lds16(pb0 + o1, db + BN * 32);
        if constexpr (BN == 256) gld_lds16(pb1 + o1, db + BN * 32 + 4096);
    };

    // prologue: 2 tiles in flight; wait tile 0 only
    stage(0, 0);
    stage(1, 1);
    vmcnt_wait<L>();
    bar();

    for (int kt = 0; kt < KT; ++kt) {
        const int c = kt & 1;
        const unsigned short* Ab = As + c * 16384 + arow;
        const unsigned short* Bb = Bs + c * (BN * 64) + brow;

        #pragma unroll
        for (int kk = 0; kk < 2; kk++) {
            bf16x8 af[8], bfr[NFR];
            #pragma unroll
            for (int mf = 0; mf < 8; mf++)
                af[mf] = *reinterpret_cast<const bf16x8*>(Ab + kk * 8192 + mf * 512);
            #pragma unroll
            for (int nf = 0; nf < NFR; nf++)
                bfr[nf] = *reinterpret_cast<const bf16x8*>(Bb + kk * BN * 32 + nf * 512);
            __builtin_amdgcn_s_setprio(1);
            #pragma unroll
            for (int mf = 0; mf < 8; mf++)
                #pragma unroll
                for (int nf = 0; nf < NFR; nf++)
                    acc[mf][nf] = __builtin_amdgcn_mfma_f32_16x16x32_bf16(af[mf], bfr[nf], acc[mf][nf], 0, 0, 0);
            __builtin_amdgcn_s_setprio(0);
            if constexpr (RS) {
                #pragma unroll
                for (int mf = 0; mf < 8; mf++)
                    #pragma unroll
                    for (int e = 0; e < 8; e++) rs[mf] += bf2f(((unsigned short*)&af[mf])[e]);
            }
        }

        if (kt == KT - 1) break;
        lgkm0();                 // this wave's reads of buf c complete (data in VGPRs)
        bar();                   // all waves done reading buf c -> safe to overwrite
        if (kt + 2 < KT) {
            stage(c, kt + 2);    // overwrite buf c with tile kt+2
            vmcnt_wait<L>();     // tile kt+1 (issued one full tile ago) landed
        } else {
            vmcnt_wait<0>();
        }
        bar();                   // buf (kt+1)&1 globally ready
    }
}

// ---------------- x f32 -> bf16 ----------------
__global__ __launch_bounds__(256) void convert_x(
    const float* __restrict__ x, unsigned short* __restrict__ xb)
{
    const size_t idx = (size_t)blockIdx.x * 256 + threadIdx.x;
    const float4* xi = reinterpret_cast<const float4*>(x) + idx * 2;
    float4 v0 = xi[0], v1 = xi[1];
    ushort4 a = { f2bf(v0.x), f2bf(v0.y), f2bf(v0.z), f2bf(v0.w) };
    ushort4 b = { f2bf(v1.x), f2bf(v1.y), f2bf(v1.z), f2bf(v1.w) };
    ushort4* xo = reinterpret_cast<ushort4*>(xb) + idx * 2;
    xo[0] = a; xo[1] = b;
}

// ---------------- W [K][N] f32 -> wT [N][K] bf16 ----------------
__global__ __launch_bounds__(256) void transpose_w(
    const float* __restrict__ w0, const float* __restrict__ w1, const float* __restrict__ w2,
    unsigned short* __restrict__ wT)
{
    __shared__ unsigned short T[64][72];
    const int z = blockIdx.z;
    const float* w = (z == 0) ? w0 : (z == 1 ? w1 : w2);
    unsigned short* o = wT + (size_t)z * 1024 * 1024;
    const int k0 = blockIdx.y * 64, n0 = blockIdx.x * 64;
    const int tid = threadIdx.x;
    const int r = tid >> 4, c4 = (tid & 15) * 4;
    #pragma unroll
    for (int i = 0; i < 4; i++) {
        int kr = r + i * 16;
        float4 v = *reinterpret_cast<const float4*>(&w[(size_t)(k0 + kr) * 1024 + n0 + c4]);
        T[c4 + 0][kr] = f2bf(v.x);
        T[c4 + 1][kr] = f2bf(v.y);
        T[c4 + 2][kr] = f2bf(v.z);
        T[c4 + 3][kr] = f2bf(v.w);
    }
    __syncthreads();
    #pragma unroll
    for (int i = 0; i < 4; i++) {
        int n = r + i * 16;
        ushort4 v = *reinterpret_cast<const ushort4*>(&T[n][c4]);
        *reinterpret_cast<ushort4*>(&o[(size_t)(n0 + n) * 1024 + k0 + c4]) = v;
    }
}

// ---------------- projections: 256x128 tiles, grid 768 ----------------
__global__ __launch_bounds__(512, 2) void proj_gemm(
    const unsigned short* __restrict__ xb, const unsigned short* __restrict__ wT,
    unsigned short* __restrict__ vk, unsigned short* __restrict__ vq,
    unsigned short* __restrict__ vvT)
{
    __shared__ unsigned short As[2 * 256 * 64], Bs[2 * 128 * 64];   // 96 KB
    const int bid = blockIdx.x;
    const int wg  = (bid & 7) * 96 + (bid >> 3);   // 768 % 8 == 0, bijective
    const int z   = wg >> 8;
    const int rem = wg & 255;
    const int bm  = (rem >> 3) * 256;
    const int bn  = (rem & 7) * 128;
    const unsigned short* Bw = wT + (size_t)z * 1024 * 1024;

    f32x4 acc[8][2] = {};
    float rs[8] = {};
    gemm8<128, 16, false>(xb, Bw, 1024, 1024, bm, bn, As, Bs, acc, rs);

    const int tid = threadIdx.x, lane = tid & 63, wave = tid >> 6;
    const int wr = wave >> 2, wc = wave & 3, lr = lane & 15, kg = lane >> 4;
    if (z < 2) {
        unsigned short* out = z ? vq : vk;
        #pragma unroll
        for (int mf = 0; mf < 8; mf++)
            #pragma unroll
            for (int nf = 0; nf < 2; nf++)
                #pragma unroll
                for (int r = 0; r < 4; r++)
                    out[(size_t)(bm + wr * 128 + mf * 16 + kg * 4 + r) * 1024
                        + bn + wc * 32 + nf * 16 + lr] = f2bf(acc[mf][nf][r]);
    } else {
        const int batch = bm >> 11;
        unsigned short* o = vvT + (size_t)batch * 1024 * 2048;
        #pragma unroll
        for (int mf = 0; mf < 8; mf++)
            #pragma unroll
            for (int nf = 0; nf < 2; nf++) {
                ushort4 v = { f2bf(acc[mf][nf][0]), f2bf(acc[mf][nf][1]),
                              f2bf(acc[mf][nf][2]), f2bf(acc[mf][nf][3]) };
                *reinterpret_cast<ushort4*>(
                    &o[(size_t)(bn + wc * 32 + nf * 16 + lr) * 2048
                       + (bm & 2047) + wr * 128 + mf * 16 + kg * 4]) = v;
            }
    }
}

// ---------------- scores: 256x256 tiles; epilogue writes exp(s/32) bf16 ----------------
__global__ __launch_bounds__(512, 2) void scores_gemm(
    const unsigned short* __restrict__ vk, const unsigned short* __restrict__ vq,
    unsigned short* __restrict__ P)
{
    __shared__ unsigned short As[2 * 256 * 64], Bs[2 * 256 * 64];   // 128 KB
    const int bid = blockIdx.x;
    const int wg  = (bid & 7) * 32 + (bid >> 3);
    const int z   = wg >> 6;
    const int rem = wg & 63;
    const int bm  = (rem >> 3) * 256;
    const int bn  = (rem & 7) * 256;
    const unsigned short* A = vk + (size_t)z * 2048 * 1024;
    const unsigned short* B = vq + (size_t)z * 2048 * 1024;
    unsigned short* out = P + (size_t)z * 2048 * 2048;

    f32x4 acc[8][4] = {};
    float rs[8] = {};
    gemm8<256, 16, false>(A, B, 1024, 1024, bm, bn, As, Bs, acc, rs);

    const int tid = threadIdx.x, lane = tid & 63, wave = tid >> 6;
    const int wr = wave >> 2, wc = wave & 3, lr = lane & 15, kg = lane >> 4;
    #pragma unroll
    for (int mf = 0; mf < 8; mf++)
        #pragma unroll
        for (int nf = 0; nf < 4; nf++)
            #pragma unroll
            for (int r = 0; r < 4; r++)
                out[(size_t)(bm + wr * 128 + mf * 16 + kg * 4 + r) * 2048
                    + bn + wc * 64 + nf * 16 + lr]
                    = f2bf(__expf(acc[mf][nf][r] * 0.03125f));
}

// ---------------- PV: 256x128 tiles, K=2048; row-sums from A-frags; out = acc/l ----------------
__global__ __launch_bounds__(512, 2) void pv_gemm(
    const unsigned short* __restrict__ P, const unsigned short* __restrict__ vvT,
    float* __restrict__ out)
{
    __shared__ unsigned short As[2 * 256 * 64], Bs[2 * 128 * 64];   // 96 KB
    const int bid = blockIdx.x;
    const int wg  = (bid & 7) * 32 + (bid >> 3);
    const int z   = wg >> 6;
    const int rem = wg & 63;
    const int bm  = (rem >> 3) * 256;
    const int bn  = (rem & 7) * 128;
    const unsigned short* A = P   + (size_t)z * 2048 * 2048;
    const unsigned short* B = vvT + (size_t)z * 1024 * 2048;
    float* o = out + (size_t)z * 2048 * 1024;

    f32x4 acc[8][2] = {};
    float rs[8] = {};
    gemm8<128, 32, true>(A, B, 2048, 2048, bm, bn, As, Bs, acc, rs);

    const int tid = threadIdx.x, lane = tid & 63, wave = tid >> 6;
    const int wr = wave >> 2, wc = wave & 3, lr = lane & 15, kg = lane >> 4;

    // rs[mf]: partial row-sum over this lane's kg k-slices; reduce across kg.
    #pragma unroll
    for (int mf = 0; mf < 8; mf++) {
        rs[mf] += __shfl_xor(rs[mf], 16);
        rs[mf] += __shfl_xor(rs[mf], 32);
    }
    #pragma unroll
    for (int mf = 0; mf < 8; mf++)
        #pragma unroll
        for (int r = 0; r < 4; r++) {
            const float l = __shfl(rs[mf], kg * 4 + r);   // row-sum for this output row
            const float inv = 1.0f / l;
            #pragma unroll
            for (int nf = 0; nf < 2; nf++)
                o[(size_t)(bm + wr * 128 + mf * 16 + kg * 4 + r) * 1024
                  + bn + wc * 32 + nf * 16 + lr] = acc[mf][nf][r] * inv;
        }
}

extern "C" void kernel_launch(void* const* d_in, const int* in_sizes, int n_in,
                              void* d_out, int out_size, void* d_ws, size_t ws_size,
                              hipStream_t stream) {
    const float* x  = (const float*)d_in[0];
    const float* wk = (const float*)d_in[1];
    const float* wq = (const float*)d_in[2];
    const float* wv = (const float*)d_in[3];
    float* out = (float*)d_out;

    char* ws = (char*)d_ws;
    const size_t MB = 1024 * 1024;
    unsigned short* xb  = (unsigned short*)(ws);             // 16MB, dead after proj
    unsigned short* wT  = (unsigned short*)(ws + 16 * MB);   // 6MB, dead after proj
    unsigned short* P   = (unsigned short*)(ws);             // 32MB bf16 exp(s), aliases xb/wT
    unsigned short* vk  = (unsigned short*)(ws + 64 * MB);
    unsigned short* vq  = (unsigned short*)(ws + 80 * MB);
    unsigned short* vvT = (unsigned short*)(ws + 96 * MB);

    convert_x  <<<dim3(4096),      256, 0, stream>>>(x, xb);
    transpose_w<<<dim3(16, 16, 3), 256, 0, stream>>>(wk, wq, wv, wT);
    proj_gemm  <<<dim3(768),       512, 0, stream>>>(xb, wT, vk, vq, vvT);
    scores_gemm<<<dim3(256),       512, 0, stream>>>(vk, vq, P);
    pv_gemm    <<<dim3(256),       512, 0, stream>>>(P, vvT, out);
}

// Round 6
// 173.993 us; speedup vs baseline: 1.2154x; 1.2154x over previous
//
#include <hip/hip_runtime.h>

// B=4, S=2048, D=1024. out = softmax((x@Wk)(x@Wq)^T / 32) @ (x@Wv), fp32 out.
// GEMMs: m97-class 128x128 tiles, 4 waves (2x2), BK=64, dbuf 64KB LDS ->
// 2 resident blocks/CU (inter-block latency hiding). Counted-vmcnt 2-deep
// pipeline, XOR-swizzled LDS (0-conflict verified geometry), XCD swizzle,
// setprio. Softmax fused: scores writes exp(s/32) bf16; pv row-sums A-frags.

typedef __attribute__((ext_vector_type(8))) short bf16x8;
typedef __attribute__((ext_vector_type(4))) float f32x4;

__device__ __forceinline__ unsigned short f2bf(float f) {
    unsigned int u = __float_as_uint(f);
    u += 0x7fff + ((u >> 16) & 1);   // RNE
    return (unsigned short)(u >> 16);
}
__device__ __forceinline__ float bf2f(unsigned short s) {
    return __uint_as_float((unsigned int)s << 16);
}

__device__ __forceinline__ void gld_lds16(const unsigned short* g, unsigned short* l) {
    __builtin_amdgcn_global_load_lds(
        (const __attribute__((address_space(1))) void*)g,
        (__attribute__((address_space(3))) void*)l, 16, 0, 0);
}

template<int N> __device__ __forceinline__ void vmcnt_wait() {
    if constexpr (N == 0) asm volatile("s_waitcnt vmcnt(0)" ::: "memory");
    else if constexpr (N == 8) asm volatile("s_waitcnt vmcnt(8)" ::: "memory");
}
__device__ __forceinline__ void bar() {
    asm volatile("" ::: "memory");
    __builtin_amdgcn_s_barrier();
    asm volatile("" ::: "memory");
}

// ---------------- 128x128x(64*KT) bf16 B^T GEMM, 4 waves (2x2) ----------------
// C[m,n] = sum_k A[bm+m,k]*B[bn+n,k]. Wave tile 64x64: acc[4][4] 16x16 frags.
// LDS per operand: 2 buf x 2 kh x [128 rows][32 bf16]; phys 16B-unit of row r
// holds global unit u ^ ((r>>1)&3)  (consecutive-8-lane groups cover all 32
// banks -> 0 conflicts, verified). Stage: inverse-swizzled global src, linear
// global_load_lds dest. 2-deep counted-vmcnt pipeline, 2 barriers/K-tile.
template<int KT, bool RS>
__device__ __forceinline__ void gemm4(
    const unsigned short* __restrict__ A, const unsigned short* __restrict__ B,
    int lda, int ldb, int bm, int bn,
    unsigned short* As, unsigned short* Bs,
    f32x4 (&acc)[4][4], float (&rs)[4])
{
    const int tid  = threadIdx.x;
    const int lane = tid & 63;
    const int wave = tid >> 6;            // 0..3
    const int wr = wave >> 1, wc = wave & 1;
    const int lr = lane & 15, kg = lane >> 4;

    // stage map: pass i, thread t -> row i*64 + (t>>2), phys unit t&3;
    // global source unit = (t&3) ^ ((t>>3)&3)   (inverse of read swizzle)
    const int srow = tid >> 2;                       // 0..63
    const int ssrc = ((tid & 3) ^ ((tid >> 3) & 3)) * 8;
    const unsigned short* pa0 = A + (size_t)(bm + srow) * lda + ssrc;
    const unsigned short* pa1 = A + (size_t)(bm + 64 + srow) * lda + ssrc;
    const unsigned short* pb0 = B + (size_t)(bn + srow) * ldb + ssrc;
    const unsigned short* pb1 = B + (size_t)(bn + 64 + srow) * ldb + ssrc;

    // read-side: ushort offset = row*32 + (kg^((lr>>1)&3))*8, kh +4096, buf +8192
    const int phys = (kg ^ ((lr >> 1) & 3)) * 8;
    const int aoff = (wr * 64 + lr) * 32 + phys;
    const int boff = (wc * 64 + lr) * 32 + phys;

    auto stage = [&](int buf, int kt) {
        unsigned short* da = As + buf * 8192 + wave * 512;
        unsigned short* db = Bs + buf * 8192 + wave * 512;
        #pragma unroll
        for (int kh = 0; kh < 2; kh++) {
            const int go = kt * 64 + kh * 32;
            gld_lds16(pa0 + go, da + kh * 4096);
            gld_lds16(pa1 + go, da + kh * 4096 + 2048);
            gld_lds16(pb0 + go, db + kh * 4096);
            gld_lds16(pb1 + go, db + kh * 4096 + 2048);
        }
    };

    // prologue: tiles 0,1 in flight; wait tile 0 only (8 loads remain)
    stage(0, 0);
    stage(1, 1);
    vmcnt_wait<8>();
    bar();

    for (int kt = 0; kt < KT; ++kt) {
        const int c = kt & 1;
        const unsigned short* Ab = As + c * 8192 + aoff;
        const unsigned short* Bb = Bs + c * 8192 + boff;

        #pragma unroll
        for (int kh = 0; kh < 2; kh++) {
            bf16x8 af[4], bf[4];
            #pragma unroll
            for (int mf = 0; mf < 4; mf++)
                af[mf] = *reinterpret_cast<const bf16x8*>(Ab + kh * 4096 + mf * 512);
            #pragma unroll
            for (int nf = 0; nf < 4; nf++)
                bf[nf] = *reinterpret_cast<const bf16x8*>(Bb + kh * 4096 + nf * 512);
            __builtin_amdgcn_s_setprio(1);
            #pragma unroll
            for (int mf = 0; mf < 4; mf++)
                #pragma unroll
                for (int nf = 0; nf < 4; nf++)
                    acc[mf][nf] = __builtin_amdgcn_mfma_f32_16x16x32_bf16(af[mf], bf[nf], acc[mf][nf], 0, 0, 0);
            __builtin_amdgcn_s_setprio(0);
            if constexpr (RS) {
                #pragma unroll
                for (int mf = 0; mf < 4; mf++)
                    #pragma unroll
                    for (int e = 0; e < 8; e++) rs[mf] += bf2f(((unsigned short*)&af[mf])[e]);
            }
        }

        if (kt == KT - 1) break;
        bar();                     // all waves done reading buf c (MFMA forced lgkmcnt)
        if (kt + 2 < KT) {
            stage(c, kt + 2);      // overwrite buf c with tile kt+2
            vmcnt_wait<8>();       // tile kt+1 (issued a full tile ago) landed
        } else {
            vmcnt_wait<0>();
        }
        bar();                     // buf (kt+1)&1 globally ready
    }
}

// ---------------- x f32 -> bf16 ----------------
__global__ __launch_bounds__(256) void convert_x(
    const float* __restrict__ x, unsigned short* __restrict__ xb)
{
    const size_t idx = (size_t)blockIdx.x * 256 + threadIdx.x;
    const float4* xi = reinterpret_cast<const float4*>(x) + idx * 2;
    float4 v0 = xi[0], v1 = xi[1];
    ushort4 a = { f2bf(v0.x), f2bf(v0.y), f2bf(v0.z), f2bf(v0.w) };
    ushort4 b = { f2bf(v1.x), f2bf(v1.y), f2bf(v1.z), f2bf(v1.w) };
    ushort4* xo = reinterpret_cast<ushort4*>(xb) + idx * 2;
    xo[0] = a; xo[1] = b;
}

// ---------------- W [K][N] f32 -> wT [N][K] bf16 ----------------
__global__ __launch_bounds__(256) void transpose_w(
    const float* __restrict__ w0, const float* __restrict__ w1, const float* __restrict__ w2,
    unsigned short* __restrict__ wT)
{
    __shared__ unsigned short T[64][72];
    const int z = blockIdx.z;
    const float* w = (z == 0) ? w0 : (z == 1 ? w1 : w2);
    unsigned short* o = wT + (size_t)z * 1024 * 1024;
    const int k0 = blockIdx.y * 64, n0 = blockIdx.x * 64;
    const int tid = threadIdx.x;
    const int r = tid >> 4, c4 = (tid & 15) * 4;
    #pragma unroll
    for (int i = 0; i < 4; i++) {
        int kr = r + i * 16;
        float4 v = *reinterpret_cast<const float4*>(&w[(size_t)(k0 + kr) * 1024 + n0 + c4]);
        T[c4 + 0][kr] = f2bf(v.x);
        T[c4 + 1][kr] = f2bf(v.y);
        T[c4 + 2][kr] = f2bf(v.z);
        T[c4 + 3][kr] = f2bf(v.w);
    }
    __syncthreads();
    #pragma unroll
    for (int i = 0; i < 4; i++) {
        int n = r + i * 16;
        ushort4 v = *reinterpret_cast<const ushort4*>(&T[n][c4]);
        *reinterpret_cast<ushort4*>(&o[(size_t)(n0 + n) * 1024 + k0 + c4]) = v;
    }
}

// ---------------- projections: 128x128 tiles, grid 1536 (3 z x 64 bm x 8 bn) ----------------
__global__ __launch_bounds__(256, 2) void proj_gemm(
    const unsigned short* __restrict__ xb, const unsigned short* __restrict__ wT,
    unsigned short* __restrict__ vk, unsigned short* __restrict__ vq,
    unsigned short* __restrict__ vvT)
{
    __shared__ unsigned short As[2 * 128 * 64], Bs[2 * 128 * 64];   // 64 KB
    const int bid = blockIdx.x;
    const int wg  = (bid & 7) * 192 + (bid >> 3);   // 1536 % 8 == 0, bijective
    const int z   = wg >> 9;
    const int rem = wg & 511;
    const int bm  = (rem >> 3) * 128;
    const int bn  = (rem & 7) * 128;
    const unsigned short* Bw = wT + (size_t)z * 1024 * 1024;

    f32x4 acc[4][4] = {};
    float rs[4] = {};
    gemm4<16, false>(xb, Bw, 1024, 1024, bm, bn, As, Bs, acc, rs);

    const int tid = threadIdx.x, lane = tid & 63, wave = tid >> 6;
    const int wr = wave >> 1, wc = wave & 1, lr = lane & 15, kg = lane >> 4;
    if (z < 2) {
        unsigned short* out = z ? vq : vk;
        #pragma unroll
        for (int mf = 0; mf < 4; mf++)
            #pragma unroll
            for (int nf = 0; nf < 4; nf++)
                #pragma unroll
                for (int r = 0; r < 4; r++)
                    out[(size_t)(bm + wr * 64 + mf * 16 + kg * 4 + r) * 1024
                        + bn + wc * 64 + nf * 16 + lr] = f2bf(acc[mf][nf][r]);
    } else {
        const int batch = bm >> 11;                 // 128-tiles never span batches
        unsigned short* o = vvT + (size_t)batch * 1024 * 2048;
        #pragma unroll
        for (int mf = 0; mf < 4; mf++)
            #pragma unroll
            for (int nf = 0; nf < 4; nf++) {
                ushort4 v = { f2bf(acc[mf][nf][0]), f2bf(acc[mf][nf][1]),
                              f2bf(acc[mf][nf][2]), f2bf(acc[mf][nf][3]) };
                *reinterpret_cast<ushort4*>(
                    &o[(size_t)(bn + wc * 64 + nf * 16 + lr) * 2048
                       + (bm & 2047) + wr * 64 + mf * 16 + kg * 4]) = v;
            }
    }
}

// ---------------- scores: 128x128 tiles, grid 1024; epilogue writes exp(s/32) bf16 ----------------
__global__ __launch_bounds__(256, 2) void scores_gemm(
    const unsigned short* __restrict__ vk, const unsigned short* __restrict__ vq,
    unsigned short* __restrict__ P)
{
    __shared__ unsigned short As[2 * 128 * 64], Bs[2 * 128 * 64];   // 64 KB
    const int bid = blockIdx.x;
    const int wg  = (bid & 7) * 128 + (bid >> 3);   // 1024 % 8 == 0
    const int z   = wg >> 8;
    const int rem = wg & 255;
    const int bm  = (rem >> 4) * 128;
    const int bn  = (rem & 15) * 128;
    const unsigned short* A = vk + (size_t)z * 2048 * 1024;
    const unsigned short* B = vq + (size_t)z * 2048 * 1024;
    unsigned short* out = P + (size_t)z * 2048 * 2048;

    f32x4 acc[4][4] = {};
    float rs[4] = {};
    gemm4<16, false>(A, B, 1024, 1024, bm, bn, As, Bs, acc, rs);

    const int tid = threadIdx.x, lane = tid & 63, wave = tid >> 6;
    const int wr = wave >> 1, wc = wave & 1, lr = lane & 15, kg = lane >> 4;
    #pragma unroll
    for (int mf = 0; mf < 4; mf++)
        #pragma unroll
        for (int nf = 0; nf < 4; nf++)
            #pragma unroll
            for (int r = 0; r < 4; r++)
                out[(size_t)(bm + wr * 64 + mf * 16 + kg * 4 + r) * 2048
                    + bn + wc * 64 + nf * 16 + lr]
                    = f2bf(__expf(acc[mf][nf][r] * 0.03125f));
}

// ---------------- PV: 128x128 tiles, K=2048, grid 512; row-sums; out = acc/l ----------------
__global__ __launch_bounds__(256, 2) void pv_gemm(
    const unsigned short* __restrict__ P, const unsigned short* __restrict__ vvT,
    float* __restrict__ out)
{
    __shared__ unsigned short As[2 * 128 * 64], Bs[2 * 128 * 64];   // 64 KB
    const int bid = blockIdx.x;
    const int wg  = (bid & 7) * 64 + (bid >> 3);    // 512 % 8 == 0
    const int z   = wg >> 7;
    const int rem = wg & 127;
    const int bm  = (rem >> 3) * 128;
    const int bn  = (rem & 7) * 128;
    const unsigned short* A = P   + (size_t)z * 2048 * 2048;
    const unsigned short* B = vvT + (size_t)z * 1024 * 2048;
    float* o = out + (size_t)z * 2048 * 1024;

    f32x4 acc[4][4] = {};
    float rs[4] = {};
    gemm4<32, true>(A, B, 2048, 2048, bm, bn, As, Bs, acc, rs);

    const int tid = threadIdx.x, lane = tid & 63, wave = tid >> 6;
    const int wr = wave >> 1, wc = wave & 1, lr = lane & 15, kg = lane >> 4;

    // rs[mf] at lane (lr,kg): partial row-sum of row wr*64+mf*16+lr over kg's octets.
    #pragma unroll
    for (int mf = 0; mf < 4; mf++) {
        rs[mf] += __shfl_xor(rs[mf], 16);
        rs[mf] += __shfl_xor(rs[mf], 32);
    }
    #pragma unroll
    for (int mf = 0; mf < 4; mf++)
        #pragma unroll
        for (int r = 0; r < 4; r++) {
            const float l = __shfl(rs[mf], kg * 4 + r);   // row-sum for this output row
            const float inv = 1.0f / l;
            #pragma unroll
            for (int nf = 0; nf < 4; nf++)
                o[(size_t)(bm + wr * 64 + mf * 16 + kg * 4 + r) * 1024
                  + bn + wc * 64 + nf * 16 + lr] = acc[mf][nf][r] * inv;
        }
}

extern "C" void kernel_launch(void* const* d_in, const int* in_sizes, int n_in,
                              void* d_out, int out_size, void* d_ws, size_t ws_size,
                              hipStream_t stream) {
    const float* x  = (const float*)d_in[0];
    const float* wk = (const float*)d_in[1];
    const float* wq = (const float*)d_in[2];
    const float* wv = (const float*)d_in[3];
    float* out = (float*)d_out;

    char* ws = (char*)d_ws;
    const size_t MB = 1024 * 1024;
    unsigned short* xb  = (unsigned short*)(ws);             // 16MB, dead after proj
    unsigned short* wT  = (unsigned short*)(ws + 16 * MB);   // 6MB, dead after proj
    unsigned short* P   = (unsigned short*)(ws);             // 32MB bf16 exp(s), aliases xb/wT
    unsigned short* vk  = (unsigned short*)(ws + 64 * MB);
    unsigned short* vq  = (unsigned short*)(ws + 80 * MB);
    unsigned short* vvT = (unsigned short*)(ws + 96 * MB);

    convert_x  <<<dim3(4096),      256, 0, stream>>>(x, xb);
    transpose_w<<<dim3(16, 16, 3), 256, 0, stream>>>(wk, wq, wv, wT);
    proj_gemm  <<<dim3(1536),      256, 0, stream>>>(xb, wT, vk, vq, vvT);
    scores_gemm<<<dim3(1024),      256, 0, stream>>>(vk, vq, P);
    pv_gemm    <<<dim3(512),       256, 0, stream>>>(P, vvT, out);
}